// Round 13
// baseline (455.872 us; speedup 1.0000x reference)
//
#include <hip/hip_runtime.h>

#define NN 100000
#define NE 3200000
#define DIN 128
#define DHID 16
#define DOUT 2
#define NBUCK 391            // ceil(NN/256) buckets of 256 dst nodes
#define EPT 16               // edges per thread in hist/fill
#define BHT 1024             // threads in hist/fill blocks
#define EPB (BHT * EPT)      // 16384 edges per block
#define NBB ((NE + EPB - 1) / EPB)  // 196
#define GTH 512              // threads in dinvb/gth kernels

// round-to-nearest-even f32 -> bf16 (bits)
__device__ __forceinline__ unsigned f2bf(float f) {
    unsigned u = __float_as_uint(f);
    return (u + 0x7FFFu + ((u >> 16) & 1u)) >> 16;
}
__device__ __forceinline__ float bflo(unsigned a) { return __uint_as_float(a << 16); }
__device__ __forceinline__ float bfhi(unsigned a) { return __uint_as_float(a & 0xFFFF0000u); }

// ---------------- bucket count zero ----------------
__global__ __launch_bounds__(512) void k_zero_b(int* __restrict__ bcount) {
    int t = threadIdx.x;
    if (t < NBUCK) bcount[t] = 0;
}

// ---------------- coarse bucket histogram (dst >> 8) ----------------
__global__ __launch_bounds__(BHT) void k_bhist(const int* __restrict__ dst,
                                               int* __restrict__ bcount) {
    __shared__ int h[NBUCK];
    int t = threadIdx.x;
    for (int i = t; i < NBUCK; i += BHT) h[i] = 0;
    __syncthreads();
    long long base = (long long)blockIdx.x * EPB;
#pragma unroll
    for (int k = 0; k < EPT; ++k) {
        long long e = base + (long long)k * BHT + t;
        if (e < NE) atomicAdd(&h[((unsigned)dst[e]) >> 8], 1);
    }
    __syncthreads();
    for (int i = t; i < NBUCK; i += BHT) {
        int c = h[i];
        if (c) atomicAdd(&bcount[i], c);
    }
}

// ---------------- scan 391 bucket counts ----------------
__global__ __launch_bounds__(512) void k_bscan(const int* __restrict__ bcount,
                                               int* __restrict__ bstart,
                                               int* __restrict__ bcursor) {
    __shared__ int sc[512];
    int t = threadIdx.x;
    int c = (t < NBUCK) ? bcount[t] : 0;
    sc[t] = c;
    __syncthreads();
    for (int off = 1; off < 512; off <<= 1) {
        int v = sc[t];
        int add = (t >= off) ? sc[t - off] : 0;
        __syncthreads();
        sc[t] = v + add;
        __syncthreads();
    }
    int excl = sc[t] - c;
    if (t <= NBUCK) bstart[t] = excl;  // bstart[NBUCK] == NE
    if (t < NBUCK) bcursor[t] = excl;
}

// ---------------- bucket the edges: packed = (dstLow<<24)|src ----------------
__global__ __launch_bounds__(BHT) void k_bfill(const int* __restrict__ src,
                                               const int* __restrict__ dst,
                                               int* __restrict__ bcursor,
                                               unsigned* __restrict__ packed) {
    __shared__ int h[NBUCK];     // local hist, then local cursor
    __shared__ int hbase[NBUCK]; // reserved global base per bucket
    int t = threadIdx.x;
    for (int i = t; i < NBUCK; i += BHT) h[i] = 0;
    __syncthreads();
    long long base = (long long)blockIdx.x * EPB;
    int ed[EPT], es[EPT];
#pragma unroll
    for (int k = 0; k < EPT; ++k) {
        long long e = base + (long long)k * BHT + t;
        if (e < NE) {
            ed[k] = dst[e];
            es[k] = src[e];
            atomicAdd(&h[((unsigned)ed[k]) >> 8], 1);
        } else {
            ed[k] = -1;
            es[k] = 0;
        }
    }
    __syncthreads();
    for (int i = t; i < NBUCK; i += BHT) {
        int c = h[i];
        hbase[i] = c ? atomicAdd(&bcursor[i], c) : 0;
    }
    __syncthreads();
    for (int i = t; i < NBUCK; i += BHT) h[i] = 0;
    __syncthreads();
#pragma unroll
    for (int k = 0; k < EPT; ++k) {
        if (ed[k] >= 0) {
            unsigned d = (unsigned)ed[k];
            int b = d >> 8;
            int off = atomicAdd(&h[b], 1);
            packed[hbase[b] + off] = ((d & 255u) << 24) | (unsigned)es[k];
        }
    }
}

// ---------------- per-bucket degree -> dinv ----------------
__global__ __launch_bounds__(GTH) void k_dinvb(const int* __restrict__ bstart,
                                               const unsigned* __restrict__ packed,
                                               float* __restrict__ dinv) {
    __shared__ int h[256];
    int b = blockIdx.x;
    int t = threadIdx.x;
    if (t < 256) h[t] = 0;
    __syncthreads();
    int ebeg = bstart[b], eend = bstart[b + 1];
    for (int e = ebeg + t; e < eend; e += GTH)
        atomicAdd(&h[packed[e] >> 24], 1);
    __syncthreads();
    int v = (b << 8) + t;
    if (t < 256 && v < NN) dinv[v] = rsqrtf((float)(h[t] + 1));
}

// ---------------- layer 1 transform: 4 lanes/node, 4 channels/lane ----------
// R4/R10-verbatim (proven no-spill, ~24 us). g1 = (x @ W1) * dinv, bf16x2.
__global__ __launch_bounds__(256) void k_mm1(const float* __restrict__ x,
                                             const float* __restrict__ W1,
                                             const float* __restrict__ dinv,
                                             unsigned* __restrict__ g1b) {
    __shared__ float Ws[DIN * DHID];  // 8 KB
    for (int i = threadIdx.x; i < DIN * DHID; i += 256) Ws[i] = W1[i];
    __syncthreads();
    int t = blockIdx.x * 256 + threadIdx.x;
    int v = t >> 2;
    int q = threadIdx.x & 3;
    if (v >= NN) return;
    float4 xq[8];
    const float4* xr = (const float4*)(x + (size_t)v * DIN + q * 32);
#pragma unroll
    for (int i = 0; i < 8; ++i) xq[i] = xr[i];
    const float* xs = (const float*)xq;
    float acc0 = 0.f, acc1 = 0.f, acc2 = 0.f, acc3 = 0.f;
    // quad-perm broadcast from quad-lane QQ: dpp_ctrl = QQ * 0x55
#define QSTEP(QQ, CTRL)                                                          \
    _Pragma("unroll")                                                            \
    for (int k = 0; k < 32; ++k) {                                               \
        float xv = __int_as_float(                                               \
            __builtin_amdgcn_mov_dpp(__float_as_int(xs[k]), CTRL, 0xF, 0xF, false)); \
        const float4 w = *(const float4*)&Ws[(QQ * 32 + k) * DHID + q * 4];      \
        acc0 += xv * w.x; acc1 += xv * w.y; acc2 += xv * w.z; acc3 += xv * w.w;  \
    }
    QSTEP(0, 0x00)
    QSTEP(1, 0x55)
    QSTEP(2, 0xAA)
    QSTEP(3, 0xFF)
#undef QSTEP
    float dv = dinv[v];
    unsigned u0 = f2bf(acc0 * dv) | (f2bf(acc1 * dv) << 16);
    unsigned u1 = f2bf(acc2 * dv) | (f2bf(acc3 * dv) << 16);
    ((uint2*)(g1b + (size_t)v * 8))[q] = make_uint2(u0, u1);
}

// ---------------- fused layer-1 gather + layer-2 transform -----------------
// One block per 256-dst bucket; acc[256][17] f32 in LDS (pad 17: stride 16
// would alias rows onto 2 banks). 8 lanes/edge, lane j owns ch 2j,2j+1;
// ds_add_f32 accumulation; 2x edge unroll. Epilogue: relu+b1, @W2 -> g2.
__global__ __launch_bounds__(GTH) void k_gth1(const int* __restrict__ bstart,
                                              const unsigned* __restrict__ packed,
                                              const float* __restrict__ dinv,
                                              const unsigned* __restrict__ G,
                                              const float* __restrict__ b1,
                                              const float* __restrict__ W2,
                                              float* __restrict__ g2) {
    __shared__ float acc[256][17];  // 17.4 KB
    int b = blockIdx.x;
    int t = threadIdx.x;
    int v0 = b << 8;
    if (t < 256) {  // self-loop init: g1[v] (already dinv[v]-scaled)
        int v = v0 + t;
        if (v < NN) {
            const uint4* gp = (const uint4*)(G + ((size_t)v << 3));
            uint4 ga = gp[0], gb = gp[1];
            acc[t][0] = bflo(ga.x);  acc[t][1] = bfhi(ga.x);
            acc[t][2] = bflo(ga.y);  acc[t][3] = bfhi(ga.y);
            acc[t][4] = bflo(ga.z);  acc[t][5] = bfhi(ga.z);
            acc[t][6] = bflo(ga.w);  acc[t][7] = bfhi(ga.w);
            acc[t][8] = bflo(gb.x);  acc[t][9] = bfhi(gb.x);
            acc[t][10] = bflo(gb.y); acc[t][11] = bfhi(gb.y);
            acc[t][12] = bflo(gb.z); acc[t][13] = bfhi(gb.z);
            acc[t][14] = bflo(gb.w); acc[t][15] = bfhi(gb.w);
        } else {
#pragma unroll
            for (int ch = 0; ch < 16; ++ch) acc[t][ch] = 0.f;
        }
    }
    __syncthreads();
    int ebeg = bstart[b], eend = bstart[b + 1];
    int slot = t >> 3, j = t & 7;
    int e = ebeg + slot;
    for (; e + 64 < eend; e += 128) {  // 64 edges in flight, 2x unroll
        unsigned pk0 = packed[e];
        unsigned pk1 = packed[e + 64];
        unsigned ga = G[((size_t)(pk0 & 0xFFFFFFu) << 3) + j];
        unsigned gb = G[((size_t)(pk1 & 0xFFFFFFu) << 3) + j];
        int d0 = pk0 >> 24;
        int d1 = pk1 >> 24;
        atomicAdd(&acc[d0][2 * j], bflo(ga));
        atomicAdd(&acc[d0][2 * j + 1], bfhi(ga));
        atomicAdd(&acc[d1][2 * j], bflo(gb));
        atomicAdd(&acc[d1][2 * j + 1], bfhi(gb));
    }
    if (e < eend) {
        unsigned pk0 = packed[e];
        unsigned ga = G[((size_t)(pk0 & 0xFFFFFFu) << 3) + j];
        int d0 = pk0 >> 24;
        atomicAdd(&acc[d0][2 * j], bflo(ga));
        atomicAdd(&acc[d0][2 * j + 1], bfhi(ga));
    }
    __syncthreads();
    if (t < 256) {  // epilogue: out1 = acc*dinv[v]; relu+b1; @W2; *dinv -> g2
        int v = v0 + t;
        if (v < NN) {
            float dv = dinv[v];
            float p0 = 0.f, p1 = 0.f;
#pragma unroll
            for (int ch = 0; ch < 16; ++ch) {
                float o = fmaxf(acc[t][ch] * dv + b1[ch], 0.f);
                p0 = fmaf(o, W2[ch * 2 + 0], p0);
                p1 = fmaf(o, W2[ch * 2 + 1], p1);
            }
            *(float2*)(g2 + (size_t)v * 2) = make_float2(p0 * dv, p1 * dv);
        }
    }
}

// ---------------- fused layer-2 gather + bias + log_softmax ----------------
__global__ __launch_bounds__(GTH) void k_gth2(const int* __restrict__ bstart,
                                              const unsigned* __restrict__ packed,
                                              const float* __restrict__ dinv,
                                              const float* __restrict__ g2,
                                              const float* __restrict__ b2,
                                              float* __restrict__ out) {
    __shared__ float acc2[256][3];
    int b = blockIdx.x;
    int t = threadIdx.x;
    int v0 = b << 8;
    if (t < 256) {  // self loop (g2 already dinv-scaled)
        int v = v0 + t;
        float2 s = (v < NN) ? *(const float2*)(g2 + (size_t)v * 2)
                            : make_float2(0.f, 0.f);
        acc2[t][0] = s.x;
        acc2[t][1] = s.y;
    }
    __syncthreads();
    int ebeg = bstart[b], eend = bstart[b + 1];
    int e = ebeg + t;
    for (; e + GTH < eend; e += 2 * GTH) {
        unsigned pk0 = packed[e];
        unsigned pk1 = packed[e + GTH];
        float2 s0 = *(const float2*)(g2 + ((size_t)(pk0 & 0xFFFFFFu) << 1));
        float2 s1 = *(const float2*)(g2 + ((size_t)(pk1 & 0xFFFFFFu) << 1));
        int d0 = pk0 >> 24;
        int d1 = pk1 >> 24;
        atomicAdd(&acc2[d0][0], s0.x);
        atomicAdd(&acc2[d0][1], s0.y);
        atomicAdd(&acc2[d1][0], s1.x);
        atomicAdd(&acc2[d1][1], s1.y);
    }
    if (e < eend) {
        unsigned pk0 = packed[e];
        float2 s0 = *(const float2*)(g2 + ((size_t)(pk0 & 0xFFFFFFu) << 1));
        int d0 = pk0 >> 24;
        atomicAdd(&acc2[d0][0], s0.x);
        atomicAdd(&acc2[d0][1], s0.y);
    }
    __syncthreads();
    if (t < 256) {
        int v = v0 + t;
        if (v < NN) {
            float dv = dinv[v];
            float a0 = acc2[t][0] * dv + b2[0];
            float a1 = acc2[t][1] * dv + b2[1];
            float m = fmaxf(a0, a1);
            float lse = m + logf(expf(a0 - m) + expf(a1 - m));
            *(float2*)(out + (size_t)v * 2) = make_float2(a0 - lse, a1 - lse);
        }
    }
}

extern "C" void kernel_launch(void* const* d_in, const int* in_sizes, int n_in,
                              void* d_out, int out_size, void* d_ws, size_t ws_size,
                              hipStream_t stream) {
    const float* x  = (const float*)d_in[0];
    const float* W1 = (const float*)d_in[1];
    const float* b1 = (const float*)d_in[2];
    const float* W2 = (const float*)d_in[3];
    const float* b2 = (const float*)d_in[4];
    const int* ei   = (const int*)d_in[5];
    const int* src = ei;
    const int* dst = ei + NE;

    // workspace (4B elems). packed stays live through gth2 -> g1b does NOT
    // alias it. No rowstart/esrc this round (pass2 eliminated).
    int* ws       = (int*)d_ws;
    int* bcount   = ws;                    // 400
    int* bstart   = ws + 400;              // 400 (uses NBUCK+1)
    int* bcursor  = ws + 800;              // 400
    float* dinv   = (float*)(ws + 1200);   // NN
    unsigned* packed = (unsigned*)(ws + 1200 + NN + 16);  // NE (16B-aligned)
    unsigned* g1b = packed + NE;           // 8*NN
    float* g2     = (float*)(g1b + 8 * NN); // 2*NN

    float* out = (float*)d_out;

    k_zero_b<<<1, 512, 0, stream>>>(bcount);
    k_bhist<<<NBB, BHT, 0, stream>>>(dst, bcount);
    k_bscan<<<1, 512, 0, stream>>>(bcount, bstart, bcursor);
    k_bfill<<<NBB, BHT, 0, stream>>>(src, dst, bcursor, packed);
    k_dinvb<<<NBUCK, GTH, 0, stream>>>(bstart, packed, dinv);
    k_mm1<<<(NN * 4 + 255) / 256, 256, 0, stream>>>(x, W1, dinv, g1b);
    k_gth1<<<NBUCK, GTH, 0, stream>>>(bstart, packed, dinv, g1b, b1, W2, g2);
    k_gth2<<<NBUCK, GTH, 0, stream>>>(bstart, packed, dinv, g2, b2, out);
}

// Round 14
// 155.005 us; speedup vs baseline: 2.9410x; 2.9410x over previous
//
#include <hip/hip_runtime.h>

#define NN 100000
#define NE 3200000
#define DIN 128
#define DHID 16
#define DOUT 2
#define NBUCK 391            // ceil(NN/256) buckets of 256 dst nodes
#define EPT 4                // edges per thread in hist/fill (R13: 16->4 for occupancy)
#define BHT 1024             // threads in hist/fill blocks
#define EPB (BHT * EPT)      // 4096 edges per block
#define NBB ((NE + EPB - 1) / EPB)  // 782
#define P2CAP 10240          // LDS edge buffer in pass2 (40 KB); avg bucket 8184

// round-to-nearest-even f32 -> bf16 (bits)
__device__ __forceinline__ unsigned f2bf(float f) {
    unsigned u = __float_as_uint(f);
    return (u + 0x7FFFu + ((u >> 16) & 1u)) >> 16;
}
__device__ __forceinline__ float bflo(unsigned a) { return __uint_as_float(a << 16); }
__device__ __forceinline__ float bfhi(unsigned a) { return __uint_as_float(a & 0xFFFF0000u); }

// ---------------- bucket count zero ----------------
__global__ __launch_bounds__(512) void k_zero_b(int* __restrict__ bcount) {
    int t = threadIdx.x;
    if (t < NBUCK) bcount[t] = 0;
}

// ---------------- coarse bucket histogram (dst >> 8) ----------------
__global__ __launch_bounds__(BHT) void k_bhist(const int* __restrict__ dst,
                                               int* __restrict__ bcount) {
    __shared__ int h[NBUCK];
    int t = threadIdx.x;
    for (int i = t; i < NBUCK; i += BHT) h[i] = 0;
    __syncthreads();
    long long base = (long long)blockIdx.x * EPB;
#pragma unroll
    for (int k = 0; k < EPT; ++k) {
        long long e = base + (long long)k * BHT + t;
        if (e < NE) atomicAdd(&h[((unsigned)dst[e]) >> 8], 1);
    }
    __syncthreads();
    for (int i = t; i < NBUCK; i += BHT) {
        int c = h[i];
        if (c) atomicAdd(&bcount[i], c);
    }
}

// ---------------- scan 391 bucket counts ----------------
__global__ __launch_bounds__(512) void k_bscan(const int* __restrict__ bcount,
                                               int* __restrict__ bstart,
                                               int* __restrict__ bcursor) {
    __shared__ int sc[512];
    int t = threadIdx.x;
    int c = (t < NBUCK) ? bcount[t] : 0;
    sc[t] = c;
    __syncthreads();
    for (int off = 1; off < 512; off <<= 1) {
        int v = sc[t];
        int add = (t >= off) ? sc[t - off] : 0;
        __syncthreads();
        sc[t] = v + add;
        __syncthreads();
    }
    int excl = sc[t] - c;
    if (t <= NBUCK) bstart[t] = excl;  // bstart[NBUCK] == NE
    if (t < NBUCK) bcursor[t] = excl;
}

// ---------------- bucket the edges: packed = (dstLow<<24)|src ----------------
__global__ __launch_bounds__(BHT) void k_bfill(const int* __restrict__ src,
                                               const int* __restrict__ dst,
                                               int* __restrict__ bcursor,
                                               unsigned* __restrict__ packed) {
    __shared__ int h[NBUCK];     // local hist, then local cursor
    __shared__ int hbase[NBUCK]; // reserved global base per bucket
    int t = threadIdx.x;
    for (int i = t; i < NBUCK; i += BHT) h[i] = 0;
    __syncthreads();
    long long base = (long long)blockIdx.x * EPB;
    int ed[EPT], es[EPT];
#pragma unroll
    for (int k = 0; k < EPT; ++k) {
        long long e = base + (long long)k * BHT + t;
        if (e < NE) {
            ed[k] = dst[e];
            es[k] = src[e];
            atomicAdd(&h[((unsigned)ed[k]) >> 8], 1);
        } else {
            ed[k] = -1;
            es[k] = 0;
        }
    }
    __syncthreads();
    for (int i = t; i < NBUCK; i += BHT) {
        int c = h[i];
        hbase[i] = c ? atomicAdd(&bcursor[i], c) : 0;
    }
    __syncthreads();
    for (int i = t; i < NBUCK; i += BHT) h[i] = 0;
    __syncthreads();
#pragma unroll
    for (int k = 0; k < EPT; ++k) {
        if (ed[k] >= 0) {
            unsigned d = (unsigned)ed[k];
            int b = d >> 8;
            int off = atomicAdd(&h[b], 1);
            packed[hbase[b] + off] = ((d & 255u) << 24) | (unsigned)es[k];
        }
    }
}

// ---------------- per-bucket exact sort -> rowstart, dinv, esrc ----------------
__global__ __launch_bounds__(256) void k_pass2(const int* __restrict__ bstart,
                                               const unsigned* __restrict__ packed,
                                               int* __restrict__ rowstart,
                                               float* __restrict__ dinv,
                                               int* __restrict__ esrc) {
    __shared__ unsigned ebuf[P2CAP];  // 40 KB
    __shared__ int h[256], sc[256], cur[256];
    int b = blockIdx.x;
    int t = threadIdx.x;
    int dst0 = b << 8;
    int ebeg = bstart[b];
    int eend = bstart[b + 1];
    int n = eend - ebeg;
    bool fits = (n <= P2CAP);
    h[t] = 0;
    __syncthreads();
    if (fits) {
        for (int i = t; i < n; i += 256) {
            unsigned pk = packed[ebeg + i];
            ebuf[i] = pk;
            atomicAdd(&h[pk >> 24], 1);
        }
    } else {
        for (int i = t; i < n; i += 256)
            atomicAdd(&h[packed[ebeg + i] >> 24], 1);
    }
    __syncthreads();
    int c = h[t];
    sc[t] = c;
    __syncthreads();
    for (int off = 1; off < 256; off <<= 1) {
        int v = sc[t];
        int add = (t >= off) ? sc[t - off] : 0;
        __syncthreads();
        sc[t] = v + add;
        __syncthreads();
    }
    int gpos = ebeg + sc[t] - c;
    int v = dst0 + t;
    if (v < NN) {
        rowstart[v] = gpos;
        dinv[v] = rsqrtf((float)(c + 1));
    }
    cur[t] = gpos;
    if (b == 0 && t == 0) rowstart[NN] = NE;
    __syncthreads();
    if (fits) {
        for (int i = t; i < n; i += 256) {
            unsigned pk = ebuf[i];
            int pos = atomicAdd(&cur[pk >> 24], 1);
            esrc[pos] = (int)(pk & 0xFFFFFFu);
        }
    } else {
        for (int i = t; i < n; i += 256) {
            unsigned pk = packed[ebeg + i];
            int pos = atomicAdd(&cur[pk >> 24], 1);
            esrc[pos] = (int)(pk & 0xFFFFFFu);
        }
    }
}

// ---------------- layer 1 transform: 4 lanes/node, 4 channels/lane ----------
// R4/R10-verbatim (proven no-spill, ~24 us). g1 = (x @ W1) * dinv, bf16x2.
__global__ __launch_bounds__(256) void k_mm1(const float* __restrict__ x,
                                             const float* __restrict__ W1,
                                             const float* __restrict__ dinv,
                                             unsigned* __restrict__ g1b) {
    __shared__ float Ws[DIN * DHID];  // 8 KB
    for (int i = threadIdx.x; i < DIN * DHID; i += 256) Ws[i] = W1[i];
    __syncthreads();
    int t = blockIdx.x * 256 + threadIdx.x;
    int v = t >> 2;
    int q = threadIdx.x & 3;
    if (v >= NN) return;
    float4 xq[8];
    const float4* xr = (const float4*)(x + (size_t)v * DIN + q * 32);
#pragma unroll
    for (int i = 0; i < 8; ++i) xq[i] = xr[i];
    const float* xs = (const float*)xq;
    float acc0 = 0.f, acc1 = 0.f, acc2 = 0.f, acc3 = 0.f;
    // quad-perm broadcast from quad-lane QQ: dpp_ctrl = QQ * 0x55
#define QSTEP(QQ, CTRL)                                                          \
    _Pragma("unroll")                                                            \
    for (int k = 0; k < 32; ++k) {                                               \
        float xv = __int_as_float(                                               \
            __builtin_amdgcn_mov_dpp(__float_as_int(xs[k]), CTRL, 0xF, 0xF, false)); \
        const float4 w = *(const float4*)&Ws[(QQ * 32 + k) * DHID + q * 4];      \
        acc0 += xv * w.x; acc1 += xv * w.y; acc2 += xv * w.z; acc3 += xv * w.w;  \
    }
    QSTEP(0, 0x00)
    QSTEP(1, 0x55)
    QSTEP(2, 0xAA)
    QSTEP(3, 0xFF)
#undef QSTEP
    float dv = dinv[v];
    unsigned u0 = f2bf(acc0 * dv) | (f2bf(acc1 * dv) << 16);
    unsigned u1 = f2bf(acc2 * dv) | (f2bf(acc3 * dv) << 16);
    ((uint2*)(g1b + (size_t)v * 8))[q] = make_uint2(u0, u1);
}

// ---------------- layer 1 gather + fused layer-2 transform ----------------
// 8 lanes/node; lane j owns channels 2j,2j+1. After the gather, each lane
// applies relu+b1 and its W2 rows, then 3 shfl_xor reduce -> g2.
__global__ __launch_bounds__(256) void k_gather1mm2(const int* __restrict__ rowstart,
                                                    const int* __restrict__ esrc,
                                                    const float* __restrict__ dinv,
                                                    const unsigned* __restrict__ G,
                                                    const float* __restrict__ b1,
                                                    const float* __restrict__ W2,
                                                    float* __restrict__ g2) {
    int t = blockIdx.x * 256 + threadIdx.x;
    int v = t >> 3;
    int j = t & 7;
    if (v >= NN) return;
    int beg = rowstart[v];
    int end = rowstart[v + 1];
    unsigned a = G[(v << 3) + j];  // self loop
    float c0 = bflo(a), c1 = bfhi(a);
    int p = beg;
    int n4 = beg + ((end - beg) & ~3);
    for (; p < n4; p += 4) {
        int u0 = esrc[p], u1 = esrc[p + 1], u2 = esrc[p + 2], u3 = esrc[p + 3];
        unsigned b0 = G[(u0 << 3) + j];
        unsigned b1w = G[(u1 << 3) + j];
        unsigned b2w = G[(u2 << 3) + j];
        unsigned b3w = G[(u3 << 3) + j];
        c0 += bflo(b0) + bflo(b1w) + bflo(b2w) + bflo(b3w);
        c1 += bfhi(b0) + bfhi(b1w) + bfhi(b2w) + bfhi(b3w);
    }
    for (; p < end; ++p) {
        unsigned b = G[(esrc[p] << 3) + j];
        c0 += bflo(b);
        c1 += bfhi(b);
    }
    float dv = dinv[v];
    // fused mm2: relu(out1 + b1) @ W2, partial over this lane's 2 channels
    float o0 = fmaxf(c0 * dv + b1[2 * j], 0.f);
    float o1 = fmaxf(c1 * dv + b1[2 * j + 1], 0.f);
    float p0 = o0 * W2[(2 * j) * 2 + 0] + o1 * W2[(2 * j + 1) * 2 + 0];
    float p1 = o0 * W2[(2 * j) * 2 + 1] + o1 * W2[(2 * j + 1) * 2 + 1];
    p0 += __shfl_xor(p0, 1); p0 += __shfl_xor(p0, 2); p0 += __shfl_xor(p0, 4);
    p1 += __shfl_xor(p1, 1); p1 += __shfl_xor(p1, 2); p1 += __shfl_xor(p1, 4);
    if (j == 0) {
        float2 w = make_float2(p0 * dv, p1 * dv);
        *(float2*)(g2 + (size_t)v * 2) = w;
    }
}

// ---------------- layer 2 gather: 8 lanes/node = 4 edge-slots x 2 ch -------
__global__ __launch_bounds__(256) void k_gather2(const int* __restrict__ rowstart,
                                                 const int* __restrict__ esrc,
                                                 const float* __restrict__ dinv,
                                                 const float* __restrict__ g2,
                                                 const float* __restrict__ b2,
                                                 float* __restrict__ out) {
    int t = blockIdx.x * 256 + threadIdx.x;
    int v = t >> 3;
    if (v >= NN) return;
    int lane = t & 7;
    int ch = lane & 1;
    int slot = lane >> 1;
    int beg = rowstart[v];
    int end = rowstart[v + 1];
    float acc = 0.0f;
    for (int p = beg + slot; p < end; p += 4)
        acc += g2[(esrc[p] << 1) + ch];
    acc += __shfl_xor(acc, 2);
    acc += __shfl_xor(acc, 4);  // all slots summed
    float o = (acc + g2[(v << 1) + ch]) * dinv[v] + b2[ch];
    float other = __shfl_xor(o, 1);
    float m = fmaxf(o, other);
    float lse = m + logf(expf(o - m) + expf(other - m));
    if (slot == 0) out[(v << 1) + ch] = o - lse;
}

extern "C" void kernel_launch(void* const* d_in, const int* in_sizes, int n_in,
                              void* d_out, int out_size, void* d_ws, size_t ws_size,
                              hipStream_t stream) {
    const float* x  = (const float*)d_in[0];
    const float* W1 = (const float*)d_in[1];
    const float* b1 = (const float*)d_in[2];
    const float* W2 = (const float*)d_in[3];
    const float* b2 = (const float*)d_in[4];
    const int* ei   = (const int*)d_in[5];
    const int* src = ei;
    const int* dst = ei + NE;

    // workspace (4B elems). packed (NE=12.8MB) is dead after k_pass2;
    // g1b (8NN uints = 3.2MB) aliases it. Stream order makes this safe.
    int* ws       = (int*)d_ws;
    int* bcount   = ws;                    // 400
    int* bstart   = ws + 400;              // 400 (uses NBUCK+1)
    int* bcursor  = ws + 800;              // 400
    int* rowstart = ws + 1200;             // NN+16
    float* dinv   = (float*)(ws + 1200 + NN + 16);    // NN
    int* esrc     = ws + 1200 + 2 * NN + 16;          // NE
    unsigned* packed = (unsigned*)(esrc + NE);        // NE
    unsigned* g1b = packed;                // 8*NN uints (aliases packed)
    float* g2     = (float*)(packed + NE); // 2*NN

    float* out = (float*)d_out;

    k_zero_b<<<1, 512, 0, stream>>>(bcount);
    k_bhist<<<NBB, BHT, 0, stream>>>(dst, bcount);
    k_bscan<<<1, 512, 0, stream>>>(bcount, bstart, bcursor);
    k_bfill<<<NBB, BHT, 0, stream>>>(src, dst, bcursor, packed);
    k_pass2<<<NBUCK, 256, 0, stream>>>(bstart, packed, rowstart, dinv, esrc);
    k_mm1<<<(NN * 4 + 255) / 256, 256, 0, stream>>>(x, W1, dinv, g1b);
    k_gather1mm2<<<(NN * 8 + 255) / 256, 256, 0, stream>>>(rowstart, esrc, dinv, g1b, b1, W2, g2);
    k_gather2<<<(NN * 8 + 255) / 256, 256, 0, stream>>>(rowstart, esrc, dinv, g2, b2, out);
}

// Round 15
// 135.173 us; speedup vs baseline: 3.3725x; 1.1467x over previous
//
#include <hip/hip_runtime.h>

#define NN 100000
#define NE 3200000
#define DIN 128
#define DHID 16
#define DOUT 2
#define NBUCK 391            // ceil(NN/256) buckets of 256 dst nodes
#define EPT 16               // edges per thread in hist/fill (16 proven best; 4 regressed)
#define BHT 1024             // threads in hist/fill blocks
#define EPB (BHT * EPT)      // 16384 edges per block
#define NBB ((NE + EPB - 1) / EPB)  // 196
#define P2CAP 10240          // LDS edge buffer in pass2 (40 KB); avg bucket 8184
#define P2T 512              // pass2 threads (R14: 256->512 for latency hiding)

// round-to-nearest-even f32 -> bf16 (bits)
__device__ __forceinline__ unsigned f2bf(float f) {
    unsigned u = __float_as_uint(f);
    return (u + 0x7FFFu + ((u >> 16) & 1u)) >> 16;
}
__device__ __forceinline__ float bflo(unsigned a) { return __uint_as_float(a << 16); }
__device__ __forceinline__ float bfhi(unsigned a) { return __uint_as_float(a & 0xFFFF0000u); }

// ---------------- bucket count zero ----------------
__global__ __launch_bounds__(512) void k_zero_b(int* __restrict__ bcount) {
    int t = threadIdx.x;
    if (t < NBUCK) bcount[t] = 0;
}

// ---------------- coarse bucket histogram (dst >> 8) ----------------
__global__ __launch_bounds__(BHT) void k_bhist(const int* __restrict__ dst,
                                               int* __restrict__ bcount) {
    __shared__ int h[NBUCK];
    int t = threadIdx.x;
    for (int i = t; i < NBUCK; i += BHT) h[i] = 0;
    __syncthreads();
    long long base = (long long)blockIdx.x * EPB;
#pragma unroll
    for (int k = 0; k < EPT; ++k) {
        long long e = base + (long long)k * BHT + t;
        if (e < NE) atomicAdd(&h[((unsigned)dst[e]) >> 8], 1);
    }
    __syncthreads();
    for (int i = t; i < NBUCK; i += BHT) {
        int c = h[i];
        if (c) atomicAdd(&bcount[i], c);
    }
}

// ---------------- scan 391 bucket counts ----------------
__global__ __launch_bounds__(512) void k_bscan(const int* __restrict__ bcount,
                                               int* __restrict__ bstart,
                                               int* __restrict__ bcursor) {
    __shared__ int sc[512];
    int t = threadIdx.x;
    int c = (t < NBUCK) ? bcount[t] : 0;
    sc[t] = c;
    __syncthreads();
    for (int off = 1; off < 512; off <<= 1) {
        int v = sc[t];
        int add = (t >= off) ? sc[t - off] : 0;
        __syncthreads();
        sc[t] = v + add;
        __syncthreads();
    }
    int excl = sc[t] - c;
    if (t <= NBUCK) bstart[t] = excl;  // bstart[NBUCK] == NE
    if (t < NBUCK) bcursor[t] = excl;
}

// ---------------- bucket the edges: packed = (dstLow<<24)|src ----------------
__global__ __launch_bounds__(BHT) void k_bfill(const int* __restrict__ src,
                                               const int* __restrict__ dst,
                                               int* __restrict__ bcursor,
                                               unsigned* __restrict__ packed) {
    __shared__ int h[NBUCK];     // local hist, then local cursor
    __shared__ int hbase[NBUCK]; // reserved global base per bucket
    int t = threadIdx.x;
    for (int i = t; i < NBUCK; i += BHT) h[i] = 0;
    __syncthreads();
    long long base = (long long)blockIdx.x * EPB;
    int ed[EPT], es[EPT];
#pragma unroll
    for (int k = 0; k < EPT; ++k) {
        long long e = base + (long long)k * BHT + t;
        if (e < NE) {
            ed[k] = dst[e];
            es[k] = src[e];
            atomicAdd(&h[((unsigned)ed[k]) >> 8], 1);
        } else {
            ed[k] = -1;
            es[k] = 0;
        }
    }
    __syncthreads();
    for (int i = t; i < NBUCK; i += BHT) {
        int c = h[i];
        hbase[i] = c ? atomicAdd(&bcursor[i], c) : 0;
    }
    __syncthreads();
    for (int i = t; i < NBUCK; i += BHT) h[i] = 0;
    __syncthreads();
#pragma unroll
    for (int k = 0; k < EPT; ++k) {
        if (ed[k] >= 0) {
            unsigned d = (unsigned)ed[k];
            int b = d >> 8;
            int off = atomicAdd(&h[b], 1);
            packed[hbase[b] + off] = ((d & 255u) << 24) | (unsigned)es[k];
        }
    }
}

// ---------------- per-bucket exact sort -> rowstart, dinv, esrc ----------------
// R14: 512 threads (was 256) — pass2 was ~1.5 waves/SIMD latency-bound.
// Scan stays 256-wide: sc padded to 512 with zeros, upper threads idle
// through the barriers (all threads execute every __syncthreads).
__global__ __launch_bounds__(P2T) void k_pass2(const int* __restrict__ bstart,
                                               const unsigned* __restrict__ packed,
                                               int* __restrict__ rowstart,
                                               float* __restrict__ dinv,
                                               int* __restrict__ esrc) {
    __shared__ unsigned ebuf[P2CAP];  // 40 KB
    __shared__ int h[256], cur[256];
    __shared__ int sc[P2T];
    int b = blockIdx.x;
    int t = threadIdx.x;
    int dst0 = b << 8;
    int ebeg = bstart[b];
    int eend = bstart[b + 1];
    int n = eend - ebeg;
    bool fits = (n <= P2CAP);
    if (t < 256) h[t] = 0;
    __syncthreads();
    if (fits) {
        for (int i = t; i < n; i += P2T) {
            unsigned pk = packed[ebeg + i];
            ebuf[i] = pk;
            atomicAdd(&h[pk >> 24], 1);
        }
    } else {
        for (int i = t; i < n; i += P2T)
            atomicAdd(&h[packed[ebeg + i] >> 24], 1);
    }
    __syncthreads();
    int c = (t < 256) ? h[t] : 0;
    sc[t] = c;
    __syncthreads();
    for (int off = 1; off < P2T; off <<= 1) {
        int v = sc[t];
        int add = (t >= off) ? sc[t - off] : 0;
        __syncthreads();
        sc[t] = v + add;
        __syncthreads();
    }
    int gpos = ebeg + sc[t] - c;  // valid for t < 256
    if (t < 256) {
        int v = dst0 + t;
        if (v < NN) {
            rowstart[v] = gpos;
            dinv[v] = rsqrtf((float)(c + 1));
        }
        cur[t] = gpos;
    }
    if (b == 0 && t == 0) rowstart[NN] = NE;
    __syncthreads();
    if (fits) {
        for (int i = t; i < n; i += P2T) {
            unsigned pk = ebuf[i];
            int pos = atomicAdd(&cur[pk >> 24], 1);
            esrc[pos] = (int)(pk & 0xFFFFFFu);
        }
    } else {
        for (int i = t; i < n; i += P2T) {
            unsigned pk = packed[ebeg + i];
            int pos = atomicAdd(&cur[pk >> 24], 1);
            esrc[pos] = (int)(pk & 0xFFFFFFu);
        }
    }
}

// ---------------- layer 1 transform: 4 lanes/node, 4 channels/lane ----------
// R4/R10-verbatim (proven no-spill, ~24 us). g1 = (x @ W1) * dinv, bf16x2.
__global__ __launch_bounds__(256) void k_mm1(const float* __restrict__ x,
                                             const float* __restrict__ W1,
                                             const float* __restrict__ dinv,
                                             unsigned* __restrict__ g1b) {
    __shared__ float Ws[DIN * DHID];  // 8 KB
    for (int i = threadIdx.x; i < DIN * DHID; i += 256) Ws[i] = W1[i];
    __syncthreads();
    int t = blockIdx.x * 256 + threadIdx.x;
    int v = t >> 2;
    int q = threadIdx.x & 3;
    if (v >= NN) return;
    float4 xq[8];
    const float4* xr = (const float4*)(x + (size_t)v * DIN + q * 32);
#pragma unroll
    for (int i = 0; i < 8; ++i) xq[i] = xr[i];
    const float* xs = (const float*)xq;
    float acc0 = 0.f, acc1 = 0.f, acc2 = 0.f, acc3 = 0.f;
    // quad-perm broadcast from quad-lane QQ: dpp_ctrl = QQ * 0x55
#define QSTEP(QQ, CTRL)                                                          \
    _Pragma("unroll")                                                            \
    for (int k = 0; k < 32; ++k) {                                               \
        float xv = __int_as_float(                                               \
            __builtin_amdgcn_mov_dpp(__float_as_int(xs[k]), CTRL, 0xF, 0xF, false)); \
        const float4 w = *(const float4*)&Ws[(QQ * 32 + k) * DHID + q * 4];      \
        acc0 += xv * w.x; acc1 += xv * w.y; acc2 += xv * w.z; acc3 += xv * w.w;  \
    }
    QSTEP(0, 0x00)
    QSTEP(1, 0x55)
    QSTEP(2, 0xAA)
    QSTEP(3, 0xFF)
#undef QSTEP
    float dv = dinv[v];
    unsigned u0 = f2bf(acc0 * dv) | (f2bf(acc1 * dv) << 16);
    unsigned u1 = f2bf(acc2 * dv) | (f2bf(acc3 * dv) << 16);
    ((uint2*)(g1b + (size_t)v * 8))[q] = make_uint2(u0, u1);
}

// ---------------- layer 1 gather + fused layer-2 transform ----------------
// 8 lanes/node; lane j owns channels 2j,2j+1. After the gather, each lane
// applies relu+b1 and its W2 rows, then 3 shfl_xor reduce -> g2.
__global__ __launch_bounds__(256) void k_gather1mm2(const int* __restrict__ rowstart,
                                                    const int* __restrict__ esrc,
                                                    const float* __restrict__ dinv,
                                                    const unsigned* __restrict__ G,
                                                    const float* __restrict__ b1,
                                                    const float* __restrict__ W2,
                                                    float* __restrict__ g2) {
    int t = blockIdx.x * 256 + threadIdx.x;
    int v = t >> 3;
    int j = t & 7;
    if (v >= NN) return;
    int beg = rowstart[v];
    int end = rowstart[v + 1];
    unsigned a = G[(v << 3) + j];  // self loop
    float c0 = bflo(a), c1 = bfhi(a);
    int p = beg;
    int n4 = beg + ((end - beg) & ~3);
    for (; p < n4; p += 4) {
        int u0 = esrc[p], u1 = esrc[p + 1], u2 = esrc[p + 2], u3 = esrc[p + 3];
        unsigned b0 = G[(u0 << 3) + j];
        unsigned b1w = G[(u1 << 3) + j];
        unsigned b2w = G[(u2 << 3) + j];
        unsigned b3w = G[(u3 << 3) + j];
        c0 += bflo(b0) + bflo(b1w) + bflo(b2w) + bflo(b3w);
        c1 += bfhi(b0) + bfhi(b1w) + bfhi(b2w) + bfhi(b3w);
    }
    for (; p < end; ++p) {
        unsigned b = G[(esrc[p] << 3) + j];
        c0 += bflo(b);
        c1 += bfhi(b);
    }
    float dv = dinv[v];
    // fused mm2: relu(out1 + b1) @ W2, partial over this lane's 2 channels
    float o0 = fmaxf(c0 * dv + b1[2 * j], 0.f);
    float o1 = fmaxf(c1 * dv + b1[2 * j + 1], 0.f);
    float p0 = o0 * W2[(2 * j) * 2 + 0] + o1 * W2[(2 * j + 1) * 2 + 0];
    float p1 = o0 * W2[(2 * j) * 2 + 1] + o1 * W2[(2 * j + 1) * 2 + 1];
    p0 += __shfl_xor(p0, 1); p0 += __shfl_xor(p0, 2); p0 += __shfl_xor(p0, 4);
    p1 += __shfl_xor(p1, 1); p1 += __shfl_xor(p1, 2); p1 += __shfl_xor(p1, 4);
    if (j == 0) {
        float2 w = make_float2(p0 * dv, p1 * dv);
        *(float2*)(g2 + (size_t)v * 2) = w;
    }
}

// ---------------- layer 2 gather: 8 lanes/node = 4 edge-slots x 2 ch -------
__global__ __launch_bounds__(256) void k_gather2(const int* __restrict__ rowstart,
                                                 const int* __restrict__ esrc,
                                                 const float* __restrict__ dinv,
                                                 const float* __restrict__ g2,
                                                 const float* __restrict__ b2,
                                                 float* __restrict__ out) {
    int t = blockIdx.x * 256 + threadIdx.x;
    int v = t >> 3;
    if (v >= NN) return;
    int lane = t & 7;
    int ch = lane & 1;
    int slot = lane >> 1;
    int beg = rowstart[v];
    int end = rowstart[v + 1];
    float acc = 0.0f;
    for (int p = beg + slot; p < end; p += 4)
        acc += g2[(esrc[p] << 1) + ch];
    acc += __shfl_xor(acc, 2);
    acc += __shfl_xor(acc, 4);  // all slots summed
    float o = (acc + g2[(v << 1) + ch]) * dinv[v] + b2[ch];
    float other = __shfl_xor(o, 1);
    float m = fmaxf(o, other);
    float lse = m + logf(expf(o - m) + expf(other - m));
    if (slot == 0) out[(v << 1) + ch] = o - lse;
}

extern "C" void kernel_launch(void* const* d_in, const int* in_sizes, int n_in,
                              void* d_out, int out_size, void* d_ws, size_t ws_size,
                              hipStream_t stream) {
    const float* x  = (const float*)d_in[0];
    const float* W1 = (const float*)d_in[1];
    const float* b1 = (const float*)d_in[2];
    const float* W2 = (const float*)d_in[3];
    const float* b2 = (const float*)d_in[4];
    const int* ei   = (const int*)d_in[5];
    const int* src = ei;
    const int* dst = ei + NE;

    // workspace (4B elems). packed (NE=12.8MB) is dead after k_pass2;
    // g1b (8NN uints = 3.2MB) aliases it. Stream order makes this safe.
    int* ws       = (int*)d_ws;
    int* bcount   = ws;                    // 400
    int* bstart   = ws + 400;              // 400 (uses NBUCK+1)
    int* bcursor  = ws + 800;              // 400
    int* rowstart = ws + 1200;             // NN+16
    float* dinv   = (float*)(ws + 1200 + NN + 16);    // NN
    int* esrc     = ws + 1200 + 2 * NN + 16;          // NE
    unsigned* packed = (unsigned*)(esrc + NE);        // NE
    unsigned* g1b = packed;                // 8*NN uints (aliases packed)
    float* g2     = (float*)(packed + NE); // 2*NN

    float* out = (float*)d_out;

    k_zero_b<<<1, 512, 0, stream>>>(bcount);
    k_bhist<<<NBB, BHT, 0, stream>>>(dst, bcount);
    k_bscan<<<1, 512, 0, stream>>>(bcount, bstart, bcursor);
    k_bfill<<<NBB, BHT, 0, stream>>>(src, dst, bcursor, packed);
    k_pass2<<<NBUCK, P2T, 0, stream>>>(bstart, packed, rowstart, dinv, esrc);
    k_mm1<<<(NN * 4 + 255) / 256, 256, 0, stream>>>(x, W1, dinv, g1b);
    k_gather1mm2<<<(NN * 8 + 255) / 256, 256, 0, stream>>>(rowstart, esrc, dinv, g1b, b1, W2, g2);
    k_gather2<<<(NN * 8 + 255) / 256, 256, 0, stream>>>(rowstart, esrc, dinv, g2, b2, out);
}

// Round 16
// 132.767 us; speedup vs baseline: 3.4336x; 1.0181x over previous
//
#include <hip/hip_runtime.h>

#define NN 100000
#define NE 3200000
#define DIN 128
#define DHID 16
#define DOUT 2
#define NBUCK 391            // ceil(NN/256) buckets of 256 dst nodes
#define EPT 16               // edges per thread in hist/fill (16 proven best; 4 regressed)
#define BHT 1024             // threads in hist/fill blocks
#define EPB (BHT * EPT)      // 16384 edges per block
#define NBB ((NE + EPB - 1) / EPB)  // 196
#define P2CAP 10240          // LDS edge buffer in pass2 (40 KB); avg bucket 8184
#define P2T 512              // pass2 threads (512 proven R14)

// round-to-nearest-even f32 -> bf16 (bits)
__device__ __forceinline__ unsigned f2bf(float f) {
    unsigned u = __float_as_uint(f);
    return (u + 0x7FFFu + ((u >> 16) & 1u)) >> 16;
}
__device__ __forceinline__ float bflo(unsigned a) { return __uint_as_float(a << 16); }
__device__ __forceinline__ float bfhi(unsigned a) { return __uint_as_float(a & 0xFFFF0000u); }

// ---------------- bucket count zero ----------------
__global__ __launch_bounds__(512) void k_zero_b(int* __restrict__ bcount) {
    int t = threadIdx.x;
    if (t < NBUCK) bcount[t] = 0;
}

// ---------------- coarse bucket histogram (dst >> 8) ----------------
__global__ __launch_bounds__(BHT) void k_bhist(const int* __restrict__ dst,
                                               int* __restrict__ bcount) {
    __shared__ int h[NBUCK];
    int t = threadIdx.x;
    for (int i = t; i < NBUCK; i += BHT) h[i] = 0;
    __syncthreads();
    long long base = (long long)blockIdx.x * EPB;
#pragma unroll
    for (int k = 0; k < EPT; ++k) {
        long long e = base + (long long)k * BHT + t;
        if (e < NE) atomicAdd(&h[((unsigned)dst[e]) >> 8], 1);
    }
    __syncthreads();
    for (int i = t; i < NBUCK; i += BHT) {
        int c = h[i];
        if (c) atomicAdd(&bcount[i], c);
    }
}

// ---------------- scan 391 bucket counts ----------------
__global__ __launch_bounds__(512) void k_bscan(const int* __restrict__ bcount,
                                               int* __restrict__ bstart,
                                               int* __restrict__ bcursor) {
    __shared__ int sc[512];
    int t = threadIdx.x;
    int c = (t < NBUCK) ? bcount[t] : 0;
    sc[t] = c;
    __syncthreads();
    for (int off = 1; off < 512; off <<= 1) {
        int v = sc[t];
        int add = (t >= off) ? sc[t - off] : 0;
        __syncthreads();
        sc[t] = v + add;
        __syncthreads();
    }
    int excl = sc[t] - c;
    if (t <= NBUCK) bstart[t] = excl;  // bstart[NBUCK] == NE
    if (t < NBUCK) bcursor[t] = excl;
}

// ---------------- bucket the edges: packed = (dstLow<<24)|src ----------------
__global__ __launch_bounds__(BHT) void k_bfill(const int* __restrict__ src,
                                               const int* __restrict__ dst,
                                               int* __restrict__ bcursor,
                                               unsigned* __restrict__ packed) {
    __shared__ int h[NBUCK];     // local hist, then local cursor
    __shared__ int hbase[NBUCK]; // reserved global base per bucket
    int t = threadIdx.x;
    for (int i = t; i < NBUCK; i += BHT) h[i] = 0;
    __syncthreads();
    long long base = (long long)blockIdx.x * EPB;
    int ed[EPT], es[EPT];
#pragma unroll
    for (int k = 0; k < EPT; ++k) {
        long long e = base + (long long)k * BHT + t;
        if (e < NE) {
            ed[k] = dst[e];
            es[k] = src[e];
            atomicAdd(&h[((unsigned)ed[k]) >> 8], 1);
        } else {
            ed[k] = -1;
            es[k] = 0;
        }
    }
    __syncthreads();
    for (int i = t; i < NBUCK; i += BHT) {
        int c = h[i];
        hbase[i] = c ? atomicAdd(&bcursor[i], c) : 0;
    }
    __syncthreads();
    for (int i = t; i < NBUCK; i += BHT) h[i] = 0;
    __syncthreads();
#pragma unroll
    for (int k = 0; k < EPT; ++k) {
        if (ed[k] >= 0) {
            unsigned d = (unsigned)ed[k];
            int b = d >> 8;
            int off = atomicAdd(&h[b], 1);
            packed[hbase[b] + off] = ((d & 255u) << 24) | (unsigned)es[k];
        }
    }
}

// ------- pass2 + fused mm1 tail: sort bucket, then transform its nodes -----
// Phases: (0) Ws load; (1) bucket hist [+LDS edge buffer]; (2) scan ->
// rowstart/dinv (dinv also kept in LDS dvs[]); (3) scatter esrc; (4) mm1 for
// this block's 256 nodes — proven 4-lane DPP loop run twice (512 thr).
// Blocks finishing their sort early start mm1 while others still scatter.
__global__ __launch_bounds__(P2T) void k_pass2mm1(const int* __restrict__ bstart,
                                                  const unsigned* __restrict__ packed,
                                                  const float* __restrict__ x,
                                                  const float* __restrict__ W1,
                                                  int* __restrict__ rowstart,
                                                  float* __restrict__ dinv,
                                                  int* __restrict__ esrc,
                                                  unsigned* __restrict__ g1b) {
    __shared__ unsigned ebuf[P2CAP];  // 40 KB
    __shared__ float Ws[DIN * DHID];  // 8 KB
    __shared__ float dvs[256];        // 1 KB
    __shared__ int h[256], cur[256];
    __shared__ int sc[P2T];
    int b = blockIdx.x;
    int t = threadIdx.x;
    int dst0 = b << 8;
    // phase 0: stage W1
    for (int i = t; i < DIN * DHID; i += P2T) Ws[i] = W1[i];
    int ebeg = bstart[b];
    int eend = bstart[b + 1];
    int n = eend - ebeg;
    bool fits = (n <= P2CAP);
    if (t < 256) h[t] = 0;
    __syncthreads();
    // phase 1: hist (+ buffer)
    if (fits) {
        for (int i = t; i < n; i += P2T) {
            unsigned pk = packed[ebeg + i];
            ebuf[i] = pk;
            atomicAdd(&h[pk >> 24], 1);
        }
    } else {
        for (int i = t; i < n; i += P2T)
            atomicAdd(&h[packed[ebeg + i] >> 24], 1);
    }
    __syncthreads();
    // phase 2: scan -> rowstart, dinv (global + LDS), cur
    int c = (t < 256) ? h[t] : 0;
    sc[t] = c;
    __syncthreads();
    for (int off = 1; off < P2T; off <<= 1) {
        int v = sc[t];
        int add = (t >= off) ? sc[t - off] : 0;
        __syncthreads();
        sc[t] = v + add;
        __syncthreads();
    }
    int gpos = ebeg + sc[t] - c;
    if (t < 256) {
        float dv = rsqrtf((float)(c + 1));
        dvs[t] = dv;
        int v = dst0 + t;
        if (v < NN) {
            rowstart[v] = gpos;
            dinv[v] = dv;
        }
        cur[t] = gpos;
    }
    if (b == 0 && t == 0) rowstart[NN] = NE;
    __syncthreads();
    // phase 3: scatter esrc
    if (fits) {
        for (int i = t; i < n; i += P2T) {
            unsigned pk = ebuf[i];
            int pos = atomicAdd(&cur[pk >> 24], 1);
            esrc[pos] = (int)(pk & 0xFFFFFFu);
        }
    } else {
        for (int i = t; i < n; i += P2T) {
            unsigned pk = packed[ebeg + i];
            int pos = atomicAdd(&cur[pk >> 24], 1);
            esrc[pos] = (int)(pk & 0xFFFFFFu);
        }
    }
    // phase 4: mm1 for this block's nodes (no barrier needed: reads Ws/dvs,
    // both synced above; does not touch ebuf/h/cur/sc)
    int q = t & 3;
#pragma unroll
    for (int half = 0; half < 2; ++half) {
        int nl = half * 128 + (t >> 2);  // node-local 0..255
        int v = dst0 + nl;
        if (v < NN) {
            float4 xq[8];
            const float4* xr = (const float4*)(x + (size_t)v * DIN + q * 32);
#pragma unroll
            for (int i = 0; i < 8; ++i) xq[i] = xr[i];
            const float* xs = (const float*)xq;
            float acc0 = 0.f, acc1 = 0.f, acc2 = 0.f, acc3 = 0.f;
#define QSTEP(QQ, CTRL)                                                          \
    _Pragma("unroll")                                                            \
    for (int k = 0; k < 32; ++k) {                                               \
        float xv = __int_as_float(                                               \
            __builtin_amdgcn_mov_dpp(__float_as_int(xs[k]), CTRL, 0xF, 0xF, false)); \
        const float4 w = *(const float4*)&Ws[(QQ * 32 + k) * DHID + q * 4];      \
        acc0 += xv * w.x; acc1 += xv * w.y; acc2 += xv * w.z; acc3 += xv * w.w;  \
    }
            QSTEP(0, 0x00)
            QSTEP(1, 0x55)
            QSTEP(2, 0xAA)
            QSTEP(3, 0xFF)
#undef QSTEP
            float dv = dvs[nl];
            unsigned u0 = f2bf(acc0 * dv) | (f2bf(acc1 * dv) << 16);
            unsigned u1 = f2bf(acc2 * dv) | (f2bf(acc3 * dv) << 16);
            ((uint2*)(g1b + (size_t)v * 8))[q] = make_uint2(u0, u1);
        }
    }
}

// ---------------- layer 1 gather + fused layer-2 transform ----------------
// 8 lanes/node; lane j owns channels 2j,2j+1. After the gather, each lane
// applies relu+b1 and its W2 rows, then 3 shfl_xor reduce -> g2.
__global__ __launch_bounds__(256) void k_gather1mm2(const int* __restrict__ rowstart,
                                                    const int* __restrict__ esrc,
                                                    const float* __restrict__ dinv,
                                                    const unsigned* __restrict__ G,
                                                    const float* __restrict__ b1,
                                                    const float* __restrict__ W2,
                                                    float* __restrict__ g2) {
    int t = blockIdx.x * 256 + threadIdx.x;
    int v = t >> 3;
    int j = t & 7;
    if (v >= NN) return;
    int beg = rowstart[v];
    int end = rowstart[v + 1];
    unsigned a = G[(v << 3) + j];  // self loop
    float c0 = bflo(a), c1 = bfhi(a);
    int p = beg;
    int n4 = beg + ((end - beg) & ~3);
    for (; p < n4; p += 4) {
        int u0 = esrc[p], u1 = esrc[p + 1], u2 = esrc[p + 2], u3 = esrc[p + 3];
        unsigned b0 = G[(u0 << 3) + j];
        unsigned b1w = G[(u1 << 3) + j];
        unsigned b2w = G[(u2 << 3) + j];
        unsigned b3w = G[(u3 << 3) + j];
        c0 += bflo(b0) + bflo(b1w) + bflo(b2w) + bflo(b3w);
        c1 += bfhi(b0) + bfhi(b1w) + bfhi(b2w) + bfhi(b3w);
    }
    for (; p < end; ++p) {
        unsigned b = G[(esrc[p] << 3) + j];
        c0 += bflo(b);
        c1 += bfhi(b);
    }
    float dv = dinv[v];
    // fused mm2: relu(out1 + b1) @ W2, partial over this lane's 2 channels
    float o0 = fmaxf(c0 * dv + b1[2 * j], 0.f);
    float o1 = fmaxf(c1 * dv + b1[2 * j + 1], 0.f);
    float p0 = o0 * W2[(2 * j) * 2 + 0] + o1 * W2[(2 * j + 1) * 2 + 0];
    float p1 = o0 * W2[(2 * j) * 2 + 1] + o1 * W2[(2 * j + 1) * 2 + 1];
    p0 += __shfl_xor(p0, 1); p0 += __shfl_xor(p0, 2); p0 += __shfl_xor(p0, 4);
    p1 += __shfl_xor(p1, 1); p1 += __shfl_xor(p1, 2); p1 += __shfl_xor(p1, 4);
    if (j == 0) {
        float2 w = make_float2(p0 * dv, p1 * dv);
        *(float2*)(g2 + (size_t)v * 2) = w;
    }
}

// ---------------- layer 2 gather: 8 lanes/node = 4 edge-slots x 2 ch -------
__global__ __launch_bounds__(256) void k_gather2(const int* __restrict__ rowstart,
                                                 const int* __restrict__ esrc,
                                                 const float* __restrict__ dinv,
                                                 const float* __restrict__ g2,
                                                 const float* __restrict__ b2,
                                                 float* __restrict__ out) {
    int t = blockIdx.x * 256 + threadIdx.x;
    int v = t >> 3;
    if (v >= NN) return;
    int lane = t & 7;
    int ch = lane & 1;
    int slot = lane >> 1;
    int beg = rowstart[v];
    int end = rowstart[v + 1];
    float acc = 0.0f;
    for (int p = beg + slot; p < end; p += 4)
        acc += g2[(esrc[p] << 1) + ch];
    acc += __shfl_xor(acc, 2);
    acc += __shfl_xor(acc, 4);  // all slots summed
    float o = (acc + g2[(v << 1) + ch]) * dinv[v] + b2[ch];
    float other = __shfl_xor(o, 1);
    float m = fmaxf(o, other);
    float lse = m + logf(expf(o - m) + expf(other - m));
    if (slot == 0) out[(v << 1) + ch] = o - lse;
}

extern "C" void kernel_launch(void* const* d_in, const int* in_sizes, int n_in,
                              void* d_out, int out_size, void* d_ws, size_t ws_size,
                              hipStream_t stream) {
    const float* x  = (const float*)d_in[0];
    const float* W1 = (const float*)d_in[1];
    const float* b1 = (const float*)d_in[2];
    const float* W2 = (const float*)d_in[3];
    const float* b2 = (const float*)d_in[4];
    const int* ei   = (const int*)d_in[5];
    const int* src = ei;
    const int* dst = ei + NE;

    // workspace (4B elems). g1b does NOT alias packed (pass2mm1 writes g1b
    // while other blocks still read packed).
    int* ws       = (int*)d_ws;
    int* bcount   = ws;                    // 400
    int* bstart   = ws + 400;              // 400 (uses NBUCK+1)
    int* bcursor  = ws + 800;              // 400
    int* rowstart = ws + 1200;             // NN+16
    float* dinv   = (float*)(ws + 1200 + NN + 16);    // NN
    int* esrc     = ws + 1200 + 2 * NN + 16;          // NE
    unsigned* packed = (unsigned*)(esrc + NE);        // NE
    unsigned* g1b = packed + NE;           // 8*NN (own region, 16B-aligned)
    float* g2     = (float*)(g1b + 8 * NN); // 2*NN

    float* out = (float*)d_out;

    k_zero_b<<<1, 512, 0, stream>>>(bcount);
    k_bhist<<<NBB, BHT, 0, stream>>>(dst, bcount);
    k_bscan<<<1, 512, 0, stream>>>(bcount, bstart, bcursor);
    k_bfill<<<NBB, BHT, 0, stream>>>(src, dst, bcursor, packed);
    k_pass2mm1<<<NBUCK, P2T, 0, stream>>>(bstart, packed, x, W1, rowstart, dinv, esrc, g1b);
    k_gather1mm2<<<(NN * 8 + 255) / 256, 256, 0, stream>>>(rowstart, esrc, dinv, g1b, b1, W2, g2);
    k_gather2<<<(NN * 8 + 255) / 256, 256, 0, stream>>>(rowstart, esrc, dinv, g2, b2, out);
}

// Round 17
// 125.688 us; speedup vs baseline: 3.6270x; 1.0563x over previous
//
#include <hip/hip_runtime.h>

#define NN 100000
#define NE 3200000
#define DIN 128
#define DHID 16
#define DOUT 2
#define NBUCK 391            // ceil(NN/256) buckets of 256 dst nodes
#define CAPSH 14             // fixed stripe: 16384 slots/bucket (mean 8192, +90 sigma)
#define CAP (1 << CAPSH)
#define EPT 16               // edges per thread in fill (16 proven best)
#define BHT 1024             // threads in fill blocks
#define EPB (BHT * EPT)      // 16384 edges per block
#define NBB ((NE + EPB - 1) / EPB)  // 196
#define P2CAP 10240          // LDS edge buffer in pass2 (40 KB); avg bucket 8192
#define P2T 512              // pass2 threads (512 proven R14)

// round-to-nearest-even f32 -> bf16 (bits)
__device__ __forceinline__ unsigned f2bf(float f) {
    unsigned u = __float_as_uint(f);
    return (u + 0x7FFFu + ((u >> 16) & 1u)) >> 16;
}
__device__ __forceinline__ float bflo(unsigned a) { return __uint_as_float(a << 16); }
__device__ __forceinline__ float bfhi(unsigned a) { return __uint_as_float(a & 0xFFFF0000u); }

// ---------------- bucket cursor zero ----------------
__global__ __launch_bounds__(512) void k_zero_b(int* __restrict__ bcursor) {
    int t = threadIdx.x;
    if (t < NBUCK) bcursor[t] = 0;
}

// ------ bucket the edges into fixed stripes: packed[b*CAP + n] ------------
// No pre-histogram needed: per-block LDS hist reserves within-bucket space
// from zero-initialized global cursors; final cursor value == bucket count.
__global__ __launch_bounds__(BHT) void k_bfill(const int* __restrict__ src,
                                               const int* __restrict__ dst,
                                               int* __restrict__ bcursor,
                                               unsigned* __restrict__ packed) {
    __shared__ int h[NBUCK];     // local hist, then local cursor
    __shared__ int hbase[NBUCK]; // reserved stripe-local base per bucket
    int t = threadIdx.x;
    for (int i = t; i < NBUCK; i += BHT) h[i] = 0;
    __syncthreads();
    long long base = (long long)blockIdx.x * EPB;
    int ed[EPT], es[EPT];
#pragma unroll
    for (int k = 0; k < EPT; ++k) {
        long long e = base + (long long)k * BHT + t;
        if (e < NE) {
            ed[k] = dst[e];
            es[k] = src[e];
            atomicAdd(&h[((unsigned)ed[k]) >> 8], 1);
        } else {
            ed[k] = -1;
            es[k] = 0;
        }
    }
    __syncthreads();
    for (int i = t; i < NBUCK; i += BHT) {
        int c = h[i];
        hbase[i] = c ? atomicAdd(&bcursor[i], c) : 0;
    }
    __syncthreads();
    for (int i = t; i < NBUCK; i += BHT) h[i] = 0;
    __syncthreads();
#pragma unroll
    for (int k = 0; k < EPT; ++k) {
        if (ed[k] >= 0) {
            unsigned d = (unsigned)ed[k];
            int b = d >> 8;
            int off = atomicAdd(&h[b], 1);
            packed[((size_t)b << CAPSH) + hbase[b] + off] =
                ((d & 255u) << 24) | (unsigned)es[k];
        }
    }
}

// ------- pass2 + fused mm1 tail: sort bucket stripe, then transform --------
// Phases: (0) Ws load; (1) bucket hist [+LDS edge buffer]; (2) scan ->
// rowstart/rowcnt/dinv (dinv kept in LDS dvs[]); (3) scatter esrc (strided);
// (4) mm1 for this block's 256 nodes (proven 4-lane DPP, 2 halves @512 thr).
__global__ __launch_bounds__(P2T) void k_pass2mm1(const int* __restrict__ bcount,
                                                  const unsigned* __restrict__ packed,
                                                  const float* __restrict__ x,
                                                  const float* __restrict__ W1,
                                                  int* __restrict__ rowstart,
                                                  int* __restrict__ rowcnt,
                                                  float* __restrict__ dinv,
                                                  int* __restrict__ esrc,
                                                  unsigned* __restrict__ g1b) {
    __shared__ unsigned ebuf[P2CAP];  // 40 KB
    __shared__ float Ws[DIN * DHID];  // 8 KB
    __shared__ float dvs[256];        // 1 KB
    __shared__ int h[256], cur[256];
    __shared__ int sc[P2T];
    int b = blockIdx.x;
    int t = threadIdx.x;
    int dst0 = b << 8;
    // phase 0: stage W1
    for (int i = t; i < DIN * DHID; i += P2T) Ws[i] = W1[i];
    int ebeg = b << CAPSH;            // stripe base
    int n = bcount[b];                // bucket count (== final bfill cursor)
    bool fits = (n <= P2CAP);
    if (t < 256) h[t] = 0;
    __syncthreads();
    // phase 1: hist (+ buffer)
    if (fits) {
        for (int i = t; i < n; i += P2T) {
            unsigned pk = packed[ebeg + i];
            ebuf[i] = pk;
            atomicAdd(&h[pk >> 24], 1);
        }
    } else {
        for (int i = t; i < n; i += P2T)
            atomicAdd(&h[packed[ebeg + i] >> 24], 1);
    }
    __syncthreads();
    // phase 2: scan -> rowstart, rowcnt, dinv (global + LDS), cur
    int c = (t < 256) ? h[t] : 0;
    sc[t] = c;
    __syncthreads();
    for (int off = 1; off < P2T; off <<= 1) {
        int v = sc[t];
        int add = (t >= off) ? sc[t - off] : 0;
        __syncthreads();
        sc[t] = v + add;
        __syncthreads();
    }
    int gpos = ebeg + sc[t] - c;
    if (t < 256) {
        float dv = rsqrtf((float)(c + 1));
        dvs[t] = dv;
        int v = dst0 + t;
        if (v < NN) {
            rowstart[v] = gpos;
            rowcnt[v] = c;
            dinv[v] = dv;
        }
        cur[t] = gpos;
    }
    __syncthreads();
    // phase 3: scatter esrc (strided, same stripe)
    if (fits) {
        for (int i = t; i < n; i += P2T) {
            unsigned pk = ebuf[i];
            int pos = atomicAdd(&cur[pk >> 24], 1);
            esrc[pos] = (int)(pk & 0xFFFFFFu);
        }
    } else {
        for (int i = t; i < n; i += P2T) {
            unsigned pk = packed[ebeg + i];
            int pos = atomicAdd(&cur[pk >> 24], 1);
            esrc[pos] = (int)(pk & 0xFFFFFFu);
        }
    }
    // phase 4: mm1 for this block's nodes (reads Ws/dvs, synced above;
    // does not touch ebuf/h/cur/sc)
    int q = t & 3;
#pragma unroll
    for (int half = 0; half < 2; ++half) {
        int nl = half * 128 + (t >> 2);  // node-local 0..255
        int v = dst0 + nl;
        if (v < NN) {
            float4 xq[8];
            const float4* xr = (const float4*)(x + (size_t)v * DIN + q * 32);
#pragma unroll
            for (int i = 0; i < 8; ++i) xq[i] = xr[i];
            const float* xs = (const float*)xq;
            float acc0 = 0.f, acc1 = 0.f, acc2 = 0.f, acc3 = 0.f;
#define QSTEP(QQ, CTRL)                                                          \
    _Pragma("unroll")                                                            \
    for (int k = 0; k < 32; ++k) {                                               \
        float xv = __int_as_float(                                               \
            __builtin_amdgcn_mov_dpp(__float_as_int(xs[k]), CTRL, 0xF, 0xF, false)); \
        const float4 w = *(const float4*)&Ws[(QQ * 32 + k) * DHID + q * 4];      \
        acc0 += xv * w.x; acc1 += xv * w.y; acc2 += xv * w.z; acc3 += xv * w.w;  \
    }
            QSTEP(0, 0x00)
            QSTEP(1, 0x55)
            QSTEP(2, 0xAA)
            QSTEP(3, 0xFF)
#undef QSTEP
            float dv = dvs[nl];
            unsigned u0 = f2bf(acc0 * dv) | (f2bf(acc1 * dv) << 16);
            unsigned u1 = f2bf(acc2 * dv) | (f2bf(acc3 * dv) << 16);
            ((uint2*)(g1b + (size_t)v * 8))[q] = make_uint2(u0, u1);
        }
    }
}

// ---------------- layer 1 gather + fused layer-2 transform ----------------
// 8 lanes/node; lane j owns channels 2j,2j+1; end = beg + rowcnt[v].
__global__ __launch_bounds__(256) void k_gather1mm2(const int* __restrict__ rowstart,
                                                    const int* __restrict__ rowcnt,
                                                    const int* __restrict__ esrc,
                                                    const float* __restrict__ dinv,
                                                    const unsigned* __restrict__ G,
                                                    const float* __restrict__ b1,
                                                    const float* __restrict__ W2,
                                                    float* __restrict__ g2) {
    int t = blockIdx.x * 256 + threadIdx.x;
    int v = t >> 3;
    int j = t & 7;
    if (v >= NN) return;
    int beg = rowstart[v];
    int end = beg + rowcnt[v];
    unsigned a = G[(v << 3) + j];  // self loop
    float c0 = bflo(a), c1 = bfhi(a);
    int p = beg;
    int n4 = beg + ((end - beg) & ~3);
    for (; p < n4; p += 4) {
        int u0 = esrc[p], u1 = esrc[p + 1], u2 = esrc[p + 2], u3 = esrc[p + 3];
        unsigned b0 = G[(u0 << 3) + j];
        unsigned b1w = G[(u1 << 3) + j];
        unsigned b2w = G[(u2 << 3) + j];
        unsigned b3w = G[(u3 << 3) + j];
        c0 += bflo(b0) + bflo(b1w) + bflo(b2w) + bflo(b3w);
        c1 += bfhi(b0) + bfhi(b1w) + bfhi(b2w) + bfhi(b3w);
    }
    for (; p < end; ++p) {
        unsigned b = G[(esrc[p] << 3) + j];
        c0 += bflo(b);
        c1 += bfhi(b);
    }
    float dv = dinv[v];
    // fused mm2: relu(out1 + b1) @ W2, partial over this lane's 2 channels
    float o0 = fmaxf(c0 * dv + b1[2 * j], 0.f);
    float o1 = fmaxf(c1 * dv + b1[2 * j + 1], 0.f);
    float p0 = o0 * W2[(2 * j) * 2 + 0] + o1 * W2[(2 * j + 1) * 2 + 0];
    float p1 = o0 * W2[(2 * j) * 2 + 1] + o1 * W2[(2 * j + 1) * 2 + 1];
    p0 += __shfl_xor(p0, 1); p0 += __shfl_xor(p0, 2); p0 += __shfl_xor(p0, 4);
    p1 += __shfl_xor(p1, 1); p1 += __shfl_xor(p1, 2); p1 += __shfl_xor(p1, 4);
    if (j == 0) {
        float2 w = make_float2(p0 * dv, p1 * dv);
        *(float2*)(g2 + (size_t)v * 2) = w;
    }
}

// ---------------- layer 2 gather: 8 lanes/node = 4 edge-slots x 2 ch -------
__global__ __launch_bounds__(256) void k_gather2(const int* __restrict__ rowstart,
                                                 const int* __restrict__ rowcnt,
                                                 const int* __restrict__ esrc,
                                                 const float* __restrict__ dinv,
                                                 const float* __restrict__ g2,
                                                 const float* __restrict__ b2,
                                                 float* __restrict__ out) {
    int t = blockIdx.x * 256 + threadIdx.x;
    int v = t >> 3;
    if (v >= NN) return;
    int lane = t & 7;
    int ch = lane & 1;
    int slot = lane >> 1;
    int beg = rowstart[v];
    int end = beg + rowcnt[v];
    float acc = 0.0f;
    for (int p = beg + slot; p < end; p += 4)
        acc += g2[(esrc[p] << 1) + ch];
    acc += __shfl_xor(acc, 2);
    acc += __shfl_xor(acc, 4);  // all slots summed
    float o = (acc + g2[(v << 1) + ch]) * dinv[v] + b2[ch];
    float other = __shfl_xor(o, 1);
    float m = fmaxf(o, other);
    float lse = m + logf(expf(o - m) + expf(other - m));
    if (slot == 0) out[(v << 1) + ch] = o - lse;
}

extern "C" void kernel_launch(void* const* d_in, const int* in_sizes, int n_in,
                              void* d_out, int out_size, void* d_ws, size_t ws_size,
                              hipStream_t stream) {
    const float* x  = (const float*)d_in[0];
    const float* W1 = (const float*)d_in[1];
    const float* b1 = (const float*)d_in[2];
    const float* W2 = (const float*)d_in[3];
    const float* b2 = (const float*)d_in[4];
    const int* ei   = (const int*)d_in[5];
    const int* src = ei;
    const int* dst = ei + NE;

    // workspace (4B elems). packed/esrc are strided: NBUCK*CAP = 6.4M each.
    int* ws       = (int*)d_ws;
    int* bcursor  = ws;                    // 400 (final value = bucket count)
    int* rowstart = ws + 400;              // NN
    int* rowcnt   = ws + 400 + NN;         // NN
    float* dinv   = (float*)(ws + 400 + 2 * NN);      // NN
    unsigned* packed = (unsigned*)(ws + 400 + 3 * NN + 12);  // NBUCK*CAP (16B-aligned)
    int* esrc     = (int*)(packed + (size_t)NBUCK * CAP);    // NBUCK*CAP
    unsigned* g1b = (unsigned*)(esrc + (size_t)NBUCK * CAP); // 8*NN
    float* g2     = (float*)(g1b + 8 * NN); // 2*NN

    float* out = (float*)d_out;

    k_zero_b<<<1, 512, 0, stream>>>(bcursor);
    k_bfill<<<NBB, BHT, 0, stream>>>(src, dst, bcursor, packed);
    k_pass2mm1<<<NBUCK, P2T, 0, stream>>>(bcursor, packed, x, W1, rowstart, rowcnt, dinv, esrc, g1b);
    k_gather1mm2<<<(NN * 8 + 255) / 256, 256, 0, stream>>>(rowstart, rowcnt, esrc, dinv, g1b, b1, W2, g2);
    k_gather2<<<(NN * 8 + 255) / 256, 256, 0, stream>>>(rowstart, rowcnt, esrc, dinv, g2, b2, out);
}

// Round 18
// 120.126 us; speedup vs baseline: 3.7950x; 1.0463x over previous
//
#include <hip/hip_runtime.h>

#define NN 100000
#define NE 3200000
#define DIN 128
#define DHID 16
#define DOUT 2
#define BSH 7                // 128 dsts per bucket (R17: 256->128 for CU fill)
#define BSZ 128
#define NBUCK ((NN + BSZ - 1) / BSZ)   // 782
#define CAPSH 13             // fixed stripe: 8192 slots/bucket (mean 4092, +64 sigma)
#define CAP (1 << CAPSH)
#define EPT 16               // edges per thread in fill (16 proven best)
#define BHT 1024             // threads in fill blocks
#define EPB (BHT * EPT)      // 16384 edges per block
#define NBB ((NE + EPB - 1) / EPB)  // 196
#define P2CAP 5120           // LDS edge buffer (20 KB); avg bucket 4092
#define P2T 512              // pass2 threads (512 proven R14)

// round-to-nearest-even f32 -> bf16 (bits)
__device__ __forceinline__ unsigned f2bf(float f) {
    unsigned u = __float_as_uint(f);
    return (u + 0x7FFFu + ((u >> 16) & 1u)) >> 16;
}
__device__ __forceinline__ float bflo(unsigned a) { return __uint_as_float(a << 16); }
__device__ __forceinline__ float bfhi(unsigned a) { return __uint_as_float(a & 0xFFFF0000u); }

// ---------------- bucket cursor zero ----------------
__global__ __launch_bounds__(1024) void k_zero_b(int* __restrict__ bcursor) {
    for (int i = threadIdx.x; i < NBUCK; i += 1024) bcursor[i] = 0;
}

// ------ bucket the edges into fixed stripes: packed[b*CAP + n] ------------
// Per-block LDS hist reserves within-bucket space from zero-initialized
// global cursors; final cursor value == bucket count.
__global__ __launch_bounds__(BHT) void k_bfill(const int* __restrict__ src,
                                               const int* __restrict__ dst,
                                               int* __restrict__ bcursor,
                                               unsigned* __restrict__ packed) {
    __shared__ int h[NBUCK];     // local hist, then local cursor
    __shared__ int hbase[NBUCK]; // reserved stripe-local base per bucket
    int t = threadIdx.x;
    for (int i = t; i < NBUCK; i += BHT) h[i] = 0;
    __syncthreads();
    long long base = (long long)blockIdx.x * EPB;
    int ed[EPT], es[EPT];
#pragma unroll
    for (int k = 0; k < EPT; ++k) {
        long long e = base + (long long)k * BHT + t;
        if (e < NE) {
            ed[k] = dst[e];
            es[k] = src[e];
            atomicAdd(&h[((unsigned)ed[k]) >> BSH], 1);
        } else {
            ed[k] = -1;
            es[k] = 0;
        }
    }
    __syncthreads();
    for (int i = t; i < NBUCK; i += BHT) {
        int c = h[i];
        hbase[i] = c ? atomicAdd(&bcursor[i], c) : 0;
    }
    __syncthreads();
    for (int i = t; i < NBUCK; i += BHT) h[i] = 0;
    __syncthreads();
#pragma unroll
    for (int k = 0; k < EPT; ++k) {
        if (ed[k] >= 0) {
            unsigned d = (unsigned)ed[k];
            int b = d >> BSH;
            int off = atomicAdd(&h[b], 1);
            packed[((size_t)b << CAPSH) + hbase[b] + off] =
                ((d & (BSZ - 1u)) << 24) | (unsigned)es[k];
        }
    }
}

// ------- pass2 + fused mm1 tail: sort bucket stripe, then transform --------
// 128-dst buckets: grid 782 blocks, ~31 KB LDS -> 5 blocks/CU capacity,
// real cross-block phase overlap (R16 had 391 blocks = 1.5/CU, 21% occ).
__global__ __launch_bounds__(P2T) void k_pass2mm1(const int* __restrict__ bcount,
                                                  const unsigned* __restrict__ packed,
                                                  const float* __restrict__ x,
                                                  const float* __restrict__ W1,
                                                  int* __restrict__ rowstart,
                                                  int* __restrict__ rowcnt,
                                                  float* __restrict__ dinv,
                                                  int* __restrict__ esrc,
                                                  unsigned* __restrict__ g1b) {
    __shared__ unsigned ebuf[P2CAP];  // 20 KB
    __shared__ float Ws[DIN * DHID];  // 8 KB
    __shared__ float dvs[BSZ];        // 512 B
    __shared__ int h[BSZ], cur[BSZ];
    __shared__ int sc[P2T];           // 2 KB
    int b = blockIdx.x;
    int t = threadIdx.x;
    int dst0 = b << BSH;
    // phase 0: stage W1
    for (int i = t; i < DIN * DHID; i += P2T) Ws[i] = W1[i];
    int ebeg = b << CAPSH;            // stripe base
    int n = bcount[b];                // bucket count (== final bfill cursor)
    bool fits = (n <= P2CAP);
    if (t < BSZ) h[t] = 0;
    __syncthreads();
    // phase 1: hist (+ buffer)
    if (fits) {
        for (int i = t; i < n; i += P2T) {
            unsigned pk = packed[ebeg + i];
            ebuf[i] = pk;
            atomicAdd(&h[pk >> 24], 1);
        }
    } else {
        for (int i = t; i < n; i += P2T)
            atomicAdd(&h[packed[ebeg + i] >> 24], 1);
    }
    __syncthreads();
    // phase 2: scan -> rowstart, rowcnt, dinv (global + LDS), cur
    int c = (t < BSZ) ? h[t] : 0;
    sc[t] = c;
    __syncthreads();
    for (int off = 1; off < P2T; off <<= 1) {
        int v = sc[t];
        int add = (t >= off) ? sc[t - off] : 0;
        __syncthreads();
        sc[t] = v + add;
        __syncthreads();
    }
    int gpos = ebeg + sc[t] - c;
    if (t < BSZ) {
        float dv = rsqrtf((float)(c + 1));
        dvs[t] = dv;
        int v = dst0 + t;
        if (v < NN) {
            rowstart[v] = gpos;
            rowcnt[v] = c;
            dinv[v] = dv;
        }
        cur[t] = gpos;
    }
    __syncthreads();
    // phase 3: scatter esrc (strided, same stripe)
    if (fits) {
        for (int i = t; i < n; i += P2T) {
            unsigned pk = ebuf[i];
            int pos = atomicAdd(&cur[pk >> 24], 1);
            esrc[pos] = (int)(pk & 0xFFFFFFu);
        }
    } else {
        for (int i = t; i < n; i += P2T) {
            unsigned pk = packed[ebeg + i];
            int pos = atomicAdd(&cur[pk >> 24], 1);
            esrc[pos] = (int)(pk & 0xFFFFFFu);
        }
    }
    // phase 4: mm1 for this block's 128 nodes (4 lanes/node, proven DPP).
    // Reads Ws/dvs (synced above); does not touch ebuf/h/cur/sc.
    int q = t & 3;
    int nl = t >> 2;  // node-local 0..127
    int v = dst0 + nl;
    if (v < NN) {
        float4 xq[8];
        const float4* xr = (const float4*)(x + (size_t)v * DIN + q * 32);
#pragma unroll
        for (int i = 0; i < 8; ++i) xq[i] = xr[i];
        const float* xs = (const float*)xq;
        float acc0 = 0.f, acc1 = 0.f, acc2 = 0.f, acc3 = 0.f;
#define QSTEP(QQ, CTRL)                                                          \
    _Pragma("unroll")                                                            \
    for (int k = 0; k < 32; ++k) {                                               \
        float xv = __int_as_float(                                               \
            __builtin_amdgcn_mov_dpp(__float_as_int(xs[k]), CTRL, 0xF, 0xF, false)); \
        const float4 w = *(const float4*)&Ws[(QQ * 32 + k) * DHID + q * 4];      \
        acc0 += xv * w.x; acc1 += xv * w.y; acc2 += xv * w.z; acc3 += xv * w.w;  \
    }
        QSTEP(0, 0x00)
        QSTEP(1, 0x55)
        QSTEP(2, 0xAA)
        QSTEP(3, 0xFF)
#undef QSTEP
        float dv = dvs[nl];
        unsigned u0 = f2bf(acc0 * dv) | (f2bf(acc1 * dv) << 16);
        unsigned u1 = f2bf(acc2 * dv) | (f2bf(acc3 * dv) << 16);
        ((uint2*)(g1b + (size_t)v * 8))[q] = make_uint2(u0, u1);
    }
}

// ---------------- layer 1 gather + fused layer-2 transform ----------------
// 8 lanes/node; lane j owns channels 2j,2j+1; end = beg + rowcnt[v].
__global__ __launch_bounds__(256) void k_gather1mm2(const int* __restrict__ rowstart,
                                                    const int* __restrict__ rowcnt,
                                                    const int* __restrict__ esrc,
                                                    const float* __restrict__ dinv,
                                                    const unsigned* __restrict__ G,
                                                    const float* __restrict__ b1,
                                                    const float* __restrict__ W2,
                                                    float* __restrict__ g2) {
    int t = blockIdx.x * 256 + threadIdx.x;
    int v = t >> 3;
    int j = t & 7;
    if (v >= NN) return;
    int beg = rowstart[v];
    int end = beg + rowcnt[v];
    unsigned a = G[(v << 3) + j];  // self loop
    float c0 = bflo(a), c1 = bfhi(a);
    int p = beg;
    int n4 = beg + ((end - beg) & ~3);
    for (; p < n4; p += 4) {
        int u0 = esrc[p], u1 = esrc[p + 1], u2 = esrc[p + 2], u3 = esrc[p + 3];
        unsigned b0 = G[(u0 << 3) + j];
        unsigned b1w = G[(u1 << 3) + j];
        unsigned b2w = G[(u2 << 3) + j];
        unsigned b3w = G[(u3 << 3) + j];
        c0 += bflo(b0) + bflo(b1w) + bflo(b2w) + bflo(b3w);
        c1 += bfhi(b0) + bfhi(b1w) + bfhi(b2w) + bfhi(b3w);
    }
    for (; p < end; ++p) {
        unsigned b = G[(esrc[p] << 3) + j];
        c0 += bflo(b);
        c1 += bfhi(b);
    }
    float dv = dinv[v];
    // fused mm2: relu(out1 + b1) @ W2, partial over this lane's 2 channels
    float o0 = fmaxf(c0 * dv + b1[2 * j], 0.f);
    float o1 = fmaxf(c1 * dv + b1[2 * j + 1], 0.f);
    float p0 = o0 * W2[(2 * j) * 2 + 0] + o1 * W2[(2 * j + 1) * 2 + 0];
    float p1 = o0 * W2[(2 * j) * 2 + 1] + o1 * W2[(2 * j + 1) * 2 + 1];
    p0 += __shfl_xor(p0, 1); p0 += __shfl_xor(p0, 2); p0 += __shfl_xor(p0, 4);
    p1 += __shfl_xor(p1, 1); p1 += __shfl_xor(p1, 2); p1 += __shfl_xor(p1, 4);
    if (j == 0) {
        float2 w = make_float2(p0 * dv, p1 * dv);
        *(float2*)(g2 + (size_t)v * 2) = w;
    }
}

// ---------------- layer 2 gather: 8 lanes/node = 4 edge-slots x 2 ch -------
__global__ __launch_bounds__(256) void k_gather2(const int* __restrict__ rowstart,
                                                 const int* __restrict__ rowcnt,
                                                 const int* __restrict__ esrc,
                                                 const float* __restrict__ dinv,
                                                 const float* __restrict__ g2,
                                                 const float* __restrict__ b2,
                                                 float* __restrict__ out) {
    int t = blockIdx.x * 256 + threadIdx.x;
    int v = t >> 3;
    if (v >= NN) return;
    int lane = t & 7;
    int ch = lane & 1;
    int slot = lane >> 1;
    int beg = rowstart[v];
    int end = beg + rowcnt[v];
    float acc = 0.0f;
    for (int p = beg + slot; p < end; p += 4)
        acc += g2[(esrc[p] << 1) + ch];
    acc += __shfl_xor(acc, 2);
    acc += __shfl_xor(acc, 4);  // all slots summed
    float o = (acc + g2[(v << 1) + ch]) * dinv[v] + b2[ch];
    float other = __shfl_xor(o, 1);
    float m = fmaxf(o, other);
    float lse = m + logf(expf(o - m) + expf(other - m));
    if (slot == 0) out[(v << 1) + ch] = o - lse;
}

extern "C" void kernel_launch(void* const* d_in, const int* in_sizes, int n_in,
                              void* d_out, int out_size, void* d_ws, size_t ws_size,
                              hipStream_t stream) {
    const float* x  = (const float*)d_in[0];
    const float* W1 = (const float*)d_in[1];
    const float* b1 = (const float*)d_in[2];
    const float* W2 = (const float*)d_in[3];
    const float* b2 = (const float*)d_in[4];
    const int* ei   = (const int*)d_in[5];
    const int* src = ei;
    const int* dst = ei + NE;

    // workspace (4B elems). packed/esrc strided: NBUCK*CAP = 6.4M each.
    int* ws       = (int*)d_ws;
    int* bcursor  = ws;                    // 800 (final value = bucket count)
    int* rowstart = ws + 800;              // NN
    int* rowcnt   = ws + 800 + NN;         // NN
    float* dinv   = (float*)(ws + 800 + 2 * NN);      // NN
    unsigned* packed = (unsigned*)(ws + 800 + 3 * NN + 12);  // NBUCK*CAP (16B-aligned)
    int* esrc     = (int*)(packed + (size_t)NBUCK * CAP);    // NBUCK*CAP
    unsigned* g1b = (unsigned*)(esrc + (size_t)NBUCK * CAP); // 8*NN
    float* g2     = (float*)(g1b + 8 * NN); // 2*NN

    float* out = (float*)d_out;

    k_zero_b<<<1, 1024, 0, stream>>>(bcursor);
    k_bfill<<<NBB, BHT, 0, stream>>>(src, dst, bcursor, packed);
    k_pass2mm1<<<NBUCK, P2T, 0, stream>>>(bcursor, packed, x, W1, rowstart, rowcnt, dinv, esrc, g1b);
    k_gather1mm2<<<(NN * 8 + 255) / 256, 256, 0, stream>>>(rowstart, rowcnt, esrc, dinv, g1b, b1, W2, g2);
    k_gather2<<<(NN * 8 + 255) / 256, 256, 0, stream>>>(rowstart, rowcnt, esrc, dinv, g2, b2, out);
}